// Round 17
// baseline (154.206 us; speedup 1.0000x reference)
//
#include <hip/hip_runtime.h>
#include <hip/hip_bf16.h>

#define NN 50000
#define NE 600000
#define TN 64                       // nodes per dst-tile
#define NT ((NN + TN - 1) / TN)     // 782 tiles
#define CAP 1024                    // bucket capacity (avg 768)

typedef unsigned short u16;
typedef unsigned int u32;
typedef unsigned long long u64;
typedef __attribute__((ext_vector_type(8))) short bf16x8;
typedef __attribute__((ext_vector_type(16))) float f32x16;
typedef __attribute__((ext_vector_type(4))) int int4v;

// ---------- LDS layout (65 KiB; 2 blocks/CU — spend spare LDS on pr double-buffer) ----------
#define SM_AB0  0        // 16K: pr buf0 [64 e][128 k] / hid (epi1 overwrites the buffer GEMM1 read)
#define SM_AB1  16384    // 16K: pr buf1
#define SM_TT   32768    // 16K: prologue ht (256B rows) -> tt [128 n1][64 d] (128B) -> upd hiddenU
#define SM_ST   49152    // 8K: St [64 e][64 d] single-buffered
#define SM_S    57344    // 8K: S  [64 d][64 e] single-buffered
#define SM_BIAS 65536    // 1K: b1m f32[128] @+0, b1u f32[128] @+512
#define SMEM_TOTAL 66560
// upd phase: ht restaged over St+S (16K contiguous @49152); aggL -> AB0; hiddenU -> TT

// LDS-only barrier: no vmcnt drain (prefetch stays in flight)
__device__ __forceinline__ void bar_lds() {
    asm volatile("s_waitcnt lgkmcnt(0)" ::: "memory");
    __builtin_amdgcn_s_barrier();
}

__device__ __forceinline__ u16 f2b(float x) {
    __hip_bfloat16 b = __float2bfloat16(x);
    union { __hip_bfloat16 b; u16 u; } c; c.b = b; return c.u;
}
__device__ __forceinline__ int4v zero4() {
    int4v v; v[0]=0; v[1]=0; v[2]=0; v[3]=0; return v;
}
__device__ __forceinline__ f32x16 zero16() {
    f32x16 z;
#pragma unroll
    for (int i = 0; i < 16; ++i) z[i] = 0.f;
    return z;
}
__device__ __forceinline__ int4v cvt8(const float* __restrict__ p) {
    const float4* q = (const float4*)p;
    float4 f0 = q[0], f1 = q[1];
    union { u16 u[8]; int4v v; } r;
    r.u[0]=f2b(f0.x); r.u[1]=f2b(f0.y); r.u[2]=f2b(f0.z); r.u[3]=f2b(f0.w);
    r.u[4]=f2b(f1.x); r.u[5]=f2b(f1.y); r.u[6]=f2b(f1.z); r.u[7]=f2b(f1.w);
    return r.v;
}
__device__ __forceinline__ u64 pack4(float a, float b, float c, float d) {
    union { u16 u[4]; u64 q; } r;
    r.u[0]=f2b(a); r.u[1]=f2b(b); r.u[2]=f2b(c); r.u[3]=f2b(d); return r.q;
}
__device__ __forceinline__ f32x16 mfma16(bf16x8 a, bf16x8 b, f32x16 c) {
    return __builtin_amdgcn_mfma_f32_32x32x16_bf16(a, b, c, 0, 0, 0);
}
// 256B-row buffers (16 chunks), 4-bit XOR swizzle
__device__ __forceinline__ bf16x8 ld256(const char* base, int row, int c) {
    return *(const bf16x8*)(base + row * 256 + ((c ^ (row & 15)) << 4));
}
// 128B-row buffers (8 chunks), 3-bit XOR swizzle
__device__ __forceinline__ bf16x8 ld128r(const char* base, int row, int c) {
    return *(const bf16x8*)(base + row * 128 + ((c ^ (row & 7)) << 4));
}

// ---------------- prep: weights -> bf16 transposed; h -> bf16 ----------------
__global__ void prep_kernel(const float* __restrict__ h,
                            const float* __restrict__ W1m, const float* __restrict__ W2m,
                            const float* __restrict__ W1u, const float* __restrict__ W2u,
                            u16* __restrict__ w1tm, u16* __restrict__ w2tm,
                            u16* __restrict__ w1tu, u16* __restrict__ w2tu,
                            u16* __restrict__ hbuf, int do_h)
{
    int tid = blockIdx.x * blockDim.x + threadIdx.x;
    int stride = gridDim.x * blockDim.x;
    for (int i = tid; i < 128 * 256; i += stride) {
        int n = i >> 8, k = i & 255;
        w1tm[i] = f2b(W1m[k * 128 + n]);
        w1tu[i] = f2b(W1u[k * 128 + n]);
    }
    for (int i = tid; i < 128 * 128; i += stride) {
        int n = i >> 7, k = i & 127;
        w2tm[i] = f2b(W2m[k * 128 + n]);
        w2tu[i] = f2b(W2u[k * 128 + n]);
    }
    if (do_h) {
        for (int i = tid; i < NN * 128 / 8; i += stride)
            *(int4v*)(hbuf + (size_t)i * 8) = cvt8(h + (size_t)i * 8);
    }
}

// ---------------- scatter: counting-bucket edges by dst tile ----------------
__global__ __launch_bounds__(256) void scatter_kernel(
    const int* __restrict__ edges, u32* __restrict__ elist, int* __restrict__ cursor)
{
    __shared__ int lcnt[NT];
    const int e0 = blockIdx.x * 2048;
    for (int i = threadIdx.x; i < NT; i += 256) lcnt[i] = 0;
    __syncthreads();
#pragma unroll
    for (int k = 0; k < 8; ++k) {
        int e = e0 + k * 256 + threadIdx.x;
        if (e < NE) atomicAdd(&lcnt[edges[2 * e + 1] >> 6], 1);
    }
    __syncthreads();
    for (int i = threadIdx.x; i < NT; i += 256) {
        int cn = lcnt[i];
        if (cn > 0) lcnt[i] = atomicAdd(&cursor[i], cn);
    }
    __syncthreads();
#pragma unroll
    for (int k = 0; k < 8; ++k) {
        int e = e0 + k * 256 + threadIdx.x;
        if (e < NE) {
            int s = edges[2 * e], d = edges[2 * e + 1];
            int bin = d >> 6;
            int pos = atomicAdd(&lcnt[bin], 1);
            if (pos < CAP) elist[(size_t)bin * CAP + pos] = (u32)s | ((u32)(d & 63) << 16);
        }
    }
}

// ---------------- fused per-dst-tile: 4 waves, each covers both e-halves ----------------
__global__ __launch_bounds__(256, 2) void fused_kernel(
    const float* __restrict__ h, const u16* __restrict__ hb, int use_hb,
    const u32* __restrict__ elist, const int* __restrict__ cursor,
    const u16* __restrict__ w1m, const u16* __restrict__ w2m,
    const u16* __restrict__ w1u, const u16* __restrict__ w2u,
    const float* __restrict__ b1m, const float* __restrict__ b2m,
    const float* __restrict__ b1u, const float* __restrict__ b2u,
    float* __restrict__ outp)
{
    extern __shared__ char sm[];
    char* ab0  = sm + SM_AB0;     // pr buf0 / hid / upd aggL
    char* ab1  = sm + SM_AB1;     // pr buf1 / hid
    char* ttr  = sm + SM_TT;      // prologue ht -> tt -> upd hiddenU
    char* Stb  = sm + SM_ST;      // St [64 e][64 d]
    char* Sb   = sm + SM_S;       // S  [64 d][64 e]
    char* bias = sm + SM_BIAS;
    char* htu  = sm + SM_ST;      // upd-phase ht (St+S dead, 16K contiguous)

    const int tid  = threadIdx.x;
    const int lane = tid & 63;
    const int wid  = tid >> 6;          // 0..3 = wn (n-block)
    const int l31  = lane & 31;
    const int kg   = lane >> 5;
    const int nrow  = wid * 32 + l31;   // output-feature index
    const int ecol0 = l31;              // e/d/node index, half 0
    const int ecol1 = 32 + l31;         // half 1

    const int bin = blockIdx.x;
    const int n0  = bin * TN;
    int size = cursor[bin]; if (size > CAP) size = CAP;
    const u32* el = elist + (size_t)bin * CAP;
    const int nchunk = (size + 63) >> 6;

    // ---- persistent weight fragments (32+32 VGPR) ----
    bf16x8 w1f[8], w2f[8];
#pragma unroll
    for (int kk = 0; kk < 8; ++kk) {
        w1f[kk] = *(const bf16x8*)(w1m + nrow * 256 + (kk * 2 + kg) * 8);   // src half
        w2f[kk] = *(const bf16x8*)(w2m + nrow * 128 + (kk * 2 + kg) * 8);
    }
    const float b2ms = b2m[nrow];

    // ---- stage prologue-ht into TT region; bias tables; zero St+S (16K) ----
    for (int i = tid; i < 1024; i += 256) {
        int row = i >> 4, c = i & 15;
        int node = n0 + row;
        int4v v = zero4();
        if (node < NN) {
            if (use_hb) v = *(const int4v*)(hb + (size_t)node * 128 + c * 8);
            else        v = cvt8(h + (size_t)node * 128 + c * 8);
        }
        *(int4v*)(ttr + row * 256 + ((c ^ (row & 15)) << 4)) = v;
    }
    if (tid < 32)      *(float4*)(bias + tid * 16)          = ((const float4*)b1m)[tid];
    else if (tid < 64) *(float4*)(bias + 512 + (tid-32)*16) = ((const float4*)b1u)[tid - 32];
    {
        char* z = sm + SM_ST + tid * 64;   // St + S = 16K
        *(int4v*)z = zero4(); *(int4v*)(z + 16) = zero4();
        *(int4v*)(z + 32) = zero4(); *(int4v*)(z + 48) = zero4();
    }

    // St writer (wave 0, same-lane ordered): row = e-slot (lane), col = d
    auto put_St = [&](u32 rec, int cb2, u16 val) {
        if (cb2 + lane < size) {
            int d = (int)((rec >> 16) & 63);
            *(u16*)(Stb + lane * 128 + (((d >> 3) ^ (lane & 7)) << 4) + (d & 7) * 2) = val;
        }
    };
    // S writer (wave 0): row = d, col = e-slot (lane)
    auto put_S = [&](u32 rec, int cb2, u16 val) {
        if (cb2 + lane < size) {
            int d = (int)((rec >> 16) & 63);
            *(u16*)(Sb + d * 128 + (((lane >> 3) ^ (d & 7)) << 4) + (lane & 7) * 2) = val;
        }
    };

    // src gather staging: thread -> rows (tid>>4 + 16u, u=0..3) x 16B chunk (tid&15)
    const int s_row0 = tid >> 4, s_cc = tid & 15;
    auto stage_load = [&](u32 dle_c, int cb2, int4v* v) {
#pragma unroll
        for (int u = 0; u < 4; ++u) {
            int row = s_row0 + 16 * u;
            int s = ((int)__shfl((int)dle_c, row, 64)) & 0xFFFF;
            v[u] = zero4();
            if (cb2 + row < size)
                v[u] = use_hb ? *(const int4v*)(hb + (size_t)s * 128 + s_cc * 8)
                              : cvt8(h + (size_t)s * 128 + s_cc * 8);
        }
    };
    auto stage_write = [&](char* base, const int4v* v) {
#pragma unroll
        for (int u = 0; u < 4; ++u) {
            int row = s_row0 + 16 * u;
            *(int4v*)(base + row * 256 + ((s_cc ^ (row & 15)) << 4)) = v[u];
        }
    };

    // in-register msg transpose: C-layout f32x16 (+bias) -> two A-frags (16 e each)
    auto mkfrags = [&](const f32x16& cc, bf16x8& lo, bf16x8& hi) {
        u32 u0,u1,u2,u3,u4,u5,u6,u7;
        {
            float a0=cc[0]+b2ms, a1=cc[1]+b2ms, a2=cc[2]+b2ms, a3=cc[3]+b2ms;
            float a4=cc[4]+b2ms, a5=cc[5]+b2ms, a6=cc[6]+b2ms, a7=cc[7]+b2ms;
            float a8=cc[8]+b2ms, a9=cc[9]+b2ms, aA=cc[10]+b2ms, aB=cc[11]+b2ms;
            float aC=cc[12]+b2ms, aD=cc[13]+b2ms, aE=cc[14]+b2ms, aF=cc[15]+b2ms;
            asm("v_cvt_pk_bf16_f32 %0, %1, %2" : "=v"(u0) : "v"(a0), "v"(a1));
            asm("v_cvt_pk_bf16_f32 %0, %1, %2" : "=v"(u1) : "v"(a2), "v"(a3));
            asm("v_cvt_pk_bf16_f32 %0, %1, %2" : "=v"(u2) : "v"(a4), "v"(a5));
            asm("v_cvt_pk_bf16_f32 %0, %1, %2" : "=v"(u3) : "v"(a6), "v"(a7));
            asm("v_cvt_pk_bf16_f32 %0, %1, %2" : "=v"(u4) : "v"(a8), "v"(a9));
            asm("v_cvt_pk_bf16_f32 %0, %1, %2" : "=v"(u5) : "v"(aA), "v"(aB));
            asm("v_cvt_pk_bf16_f32 %0, %1, %2" : "=v"(u6) : "v"(aC), "v"(aD));
            asm("v_cvt_pk_bf16_f32 %0, %1, %2" : "=v"(u7) : "v"(aE), "v"(aF));
        }
        asm volatile("v_permlane32_swap_b32 %0, %1" : "+v"(u0), "+v"(u2));
        asm volatile("v_permlane32_swap_b32 %0, %1" : "+v"(u1), "+v"(u3));
        asm volatile("v_permlane32_swap_b32 %0, %1" : "+v"(u4), "+v"(u6));
        asm volatile("v_permlane32_swap_b32 %0, %1" : "+v"(u5), "+v"(u7));
        union { u32 w[4]; bf16x8 v; } A, B;
        A.w[0]=u0; A.w[1]=u1; A.w[2]=u2; A.w[3]=u3;
        B.w[0]=u4; B.w[1]=u5; B.w[2]=u6; B.w[3]=u7;
        lo = A.v; hi = B.v;
    };

    u32 dle    = (lane < size) ? el[lane] : 0u;             // chunk 0 records
    u32 dle_nx = (64 + lane < size) ? el[64 + lane] : 0u;   // chunk 1 records (resident 1 ahead)
    if (nchunk > 0) {
        int4v v[4];
        stage_load(dle, 0, v);
        stage_write(ab0, v);
    }
    __syncthreads();   // ht(ttr) / bias / St+S-zero / pr0 ready

    // ---- T-compute: reads ht from TT region; wave0 sets St+S for chunk 0 ----
    f32x16 t0 = zero16(), t1 = zero16();
    {
        __builtin_amdgcn_s_setprio(1);
#pragma unroll
        for (int kk = 0; kk < 8; ++kk) {
            bf16x8 wtf = *(const bf16x8*)(w1m + nrow * 256 + (16 + kk * 2 + kg) * 8);
            int ch = kk * 2 + kg;
            t0 = mfma16(wtf, ld256(ttr, ecol0, ch), t0);
            t1 = mfma16(wtf, ld256(ttr, ecol1, ch), t1);
        }
        __builtin_amdgcn_s_setprio(0);
    }
    if (wid == 0) { put_St(dle, 0, 0x3F80); put_S(dle, 0, 0x3F80); }
    bar_lds();   // all ht reads done -> TT region reusable as tt

    // write Tt into TT region ([128 n1][64 d], 128B rows, 3-bit swz)
#pragma unroll
    for (int r = 0; r < 16; ++r) {
        int n1 = wid * 32 + (r & 3) + 8 * (r >> 2) + 4 * kg;
        *(u16*)(ttr + n1 * 128 + (((ecol0 >> 3) ^ (n1 & 7)) << 4) + (ecol0 & 7) * 2) = f2b(t0[r]);
        *(u16*)(ttr + n1 * 128 + (((ecol1 >> 3) ^ (n1 & 7)) << 4) + (ecol1 & 7) * 2) = f2b(t1[r]);
    }
    bar_lds();   // tt + St + S ready

    // ---- chunk loop: 3 barriers ----
    f32x16 aggT0 = zero16(), aggT1 = zero16();
    u32 dle_prev = 0;
    for (int c = 0; c < nchunk; ++c) {
        const int cb = c << 6;
        const bool havepf  = (c + 1 < nchunk);
        char* prc = (c & 1) ? ab1 : ab0;
        char* prn = (c & 1) ? ab0 : ab1;

        // ---- P0: gather issue (dle_nx resident -> no el-load chain); el prefetch; GEMM1 ----
        int4v v[4];
        if (havepf) stage_load(dle_nx, cb + 64, v);
        u32 dle_nx2 = (c + 2 < nchunk && cb + 128 + lane < size) ? el[cb + 128 + lane] : 0u;

        f32x16 mm0 = zero16(), mm1 = zero16();
        __builtin_amdgcn_s_setprio(1);
#pragma unroll
        for (int kk = 0; kk < 4; ++kk) {
            int ch = kk * 2 + kg;
            bf16x8 ttf = ld128r(ttr, nrow, ch);           // shared across halves
            mm0 = mfma16(ttf, ld128r(Stb, ecol0, ch), mm0);
            mm1 = mfma16(ttf, ld128r(Stb, ecol1, ch), mm1);
        }
#pragma unroll
        for (int kk = 0; kk < 8; ++kk) {
            int ch = kk * 2 + kg;
            mm0 = mfma16(w1f[kk], ld256(prc, ecol0, ch), mm0);
            mm1 = mfma16(w1f[kk], ld256(prc, ecol1, ch), mm1);
        }
        __builtin_amdgcn_s_setprio(0);
        bar_lds();   // pr[cur] + St reads done

        // ---- P1: epi1 -> hid (prc); stage_write -> prn; wave0 St/S maint ----
#pragma unroll
        for (int rq = 0; rq < 4; ++rq) {
            float4 bq = *(const float4*)(bias + (wid * 32 + 8 * rq + 4 * kg) * 4);
            int cch = wid * 4 + rq;
            u64 q0 = pack4(fmaxf(mm0[4 * rq + 0] + bq.x, 0.f),
                           fmaxf(mm0[4 * rq + 1] + bq.y, 0.f),
                           fmaxf(mm0[4 * rq + 2] + bq.z, 0.f),
                           fmaxf(mm0[4 * rq + 3] + bq.w, 0.f));
            u64 q1 = pack4(fmaxf(mm1[4 * rq + 0] + bq.x, 0.f),
                           fmaxf(mm1[4 * rq + 1] + bq.y, 0.f),
                           fmaxf(mm1[4 * rq + 2] + bq.z, 0.f),
                           fmaxf(mm1[4 * rq + 3] + bq.w, 0.f));
            *(u64*)(prc + ecol0 * 256 + ((cch ^ (ecol0 & 15)) << 4) + 8 * kg) = q0;
            *(u64*)(prc + ecol1 * 256 + ((cch ^ (ecol1 & 15)) << 4) + 8 * kg) = q1;
        }
        if (havepf) stage_write(prn, v);     // compiler inserts precise vmcnt before writes
        if (wid == 0) {
            if (c > 0) put_S(dle_prev, cb - 64, 0);   // clear prev S (reads done at P2(c-1) bar)
            put_St(dle, cb, 0);                       // clear cur St (reads done at P0 bar)
            asm volatile("s_waitcnt lgkmcnt(0)" ::: "memory");
            put_St(dle_nx, cb + 64, 0x3F80);          // set next St (no-op past end)
            put_S(dle, cb, 0x3F80);                   // (re)set cur S for P2
        }
        bar_lds();   // hid + pr[next] ready; St/S updated

        // ---- P2: GEMM2 -> c20/c21; in-reg transpose; segsum aggT += msg @ S ----
        {
            f32x16 c20 = zero16(), c21 = zero16();
            __builtin_amdgcn_s_setprio(1);
#pragma unroll
            for (int kk = 0; kk < 8; ++kk) {
                int ch = kk * 2 + kg;
                c20 = mfma16(ld256(prc, ecol0, ch), w2f[kk], c20);
                c21 = mfma16(ld256(prc, ecol1, ch), w2f[kk], c21);
            }
            __builtin_amdgcn_s_setprio(0);
            bf16x8 fA, fB, fC, fD;
            mkfrags(c20, fA, fB);     // e 0..15, 16..31
            mkfrags(c21, fC, fD);     // e 32..47, 48..63
            __builtin_amdgcn_s_setprio(1);
            aggT0 = mfma16(fA, ld128r(Sb, ecol0, 0 + kg), aggT0);
            aggT1 = mfma16(fA, ld128r(Sb, ecol1, 0 + kg), aggT1);
            aggT0 = mfma16(fB, ld128r(Sb, ecol0, 2 + kg), aggT0);
            aggT1 = mfma16(fB, ld128r(Sb, ecol1, 2 + kg), aggT1);
            aggT0 = mfma16(fC, ld128r(Sb, ecol0, 4 + kg), aggT0);
            aggT1 = mfma16(fC, ld128r(Sb, ecol1, 4 + kg), aggT1);
            aggT0 = mfma16(fD, ld128r(Sb, ecol0, 6 + kg), aggT0);
            aggT1 = mfma16(fD, ld128r(Sb, ecol1, 6 + kg), aggT1);
            __builtin_amdgcn_s_setprio(0);
        }
        bar_lds();   // hid reads + S reads done

        dle_prev = dle;
        dle = dle_nx;
        dle_nx = dle_nx2;
    }

    // ---- upd phase: dump aggT -> aggL in ab0; restage ht into St+S region ----
#pragma unroll
    for (int rq = 0; rq < 4; ++rq) {
        int cch = wid * 4 + rq;
        u64 q0 = pack4(aggT0[4 * rq + 0], aggT0[4 * rq + 1], aggT0[4 * rq + 2], aggT0[4 * rq + 3]);
        u64 q1 = pack4(aggT1[4 * rq + 0], aggT1[4 * rq + 1], aggT1[4 * rq + 2], aggT1[4 * rq + 3]);
        *(u64*)(ab0 + ecol0 * 256 + ((cch ^ (ecol0 & 15)) << 4) + 8 * kg) = q0;
        *(u64*)(ab0 + ecol1 * 256 + ((cch ^ (ecol1 & 15)) << 4) + 8 * kg) = q1;
    }
    for (int i = tid; i < 1024; i += 256) {
        int row = i >> 4, c = i & 15;
        int node = n0 + row;
        int4v v = zero4();
        if (node < NN) {
            if (use_hb) v = *(const int4v*)(hb + (size_t)node * 128 + c * 8);
            else        v = cvt8(h + (size_t)node * 128 + c * 8);
        }
        *(int4v*)(htu + row * 256 + ((c ^ (row & 15)) << 4)) = v;
    }
    bar_lds();   // aggL + ht ready

    // upd GEMM1 (swapped): au[n1][node] = W1u @ [ht | aggL]^T
    {
        f32x16 au0 = zero16(), au1 = zero16();
        {
            bf16x8 wa[8];
#pragma unroll
            for (int kk = 0; kk < 8; ++kk)
                wa[kk] = *(const bf16x8*)(w1u + nrow * 256 + (kk * 2 + kg) * 8);
            __builtin_amdgcn_s_setprio(1);
#pragma unroll
            for (int kk = 0; kk < 8; ++kk) {
                int ch = kk * 2 + kg;
                au0 = mfma16(wa[kk], ld256(htu, ecol0, ch), au0);
                au1 = mfma16(wa[kk], ld256(htu, ecol1, ch), au1);
            }
            __builtin_amdgcn_s_setprio(0);
        }
        {
            bf16x8 wbf[8];
#pragma unroll
            for (int kk = 0; kk < 8; ++kk)
                wbf[kk] = *(const bf16x8*)(w1u + nrow * 256 + ((8 + kk) * 2 + kg) * 8);
            __builtin_amdgcn_s_setprio(1);
#pragma unroll
            for (int kk = 0; kk < 8; ++kk) {
                int ch = kk * 2 + kg;
                au0 = mfma16(wbf[kk], ld256(ab0, ecol0, ch), au0);
                au1 = mfma16(wbf[kk], ld256(ab0, ecol1, ch), au1);
            }
            __builtin_amdgcn_s_setprio(0);
        }
        bar_lds();   // tt reads long done; TT region writable (hiddenU)
        // epiU1 -> hiddenU[node][n1] into TT region (256B rows), bias from LDS
#pragma unroll
        for (int rq = 0; rq < 4; ++rq) {
            float4 bq = *(const float4*)(bias + 512 + (wid * 32 + 8 * rq + 4 * kg) * 4);
            int cch = wid * 4 + rq;
            u64 q0 = pack4(fmaxf(au0[4 * rq + 0] + bq.x, 0.f),
                           fmaxf(au0[4 * rq + 1] + bq.y, 0.f),
                           fmaxf(au0[4 * rq + 2] + bq.z, 0.f),
                           fmaxf(au0[4 * rq + 3] + bq.w, 0.f));
            u64 q1 = pack4(fmaxf(au1[4 * rq + 0] + bq.x, 0.f),
                           fmaxf(au1[4 * rq + 1] + bq.y, 0.f),
                           fmaxf(au1[4 * rq + 2] + bq.z, 0.f),
                           fmaxf(au1[4 * rq + 3] + bq.w, 0.f));
            *(u64*)(ttr + ecol0 * 256 + ((cch ^ (ecol0 & 15)) << 4) + 8 * kg) = q0;
            *(u64*)(ttr + ecol1 * 256 + ((cch ^ (ecol1 & 15)) << 4) + 8 * kg) = q1;
        }
    }
    bar_lds();

    // upd GEMM2 (direct): out[node][n2] = hiddenU @ W2u + b2u + h
    {
        bf16x8 wc[8];
#pragma unroll
        for (int kk = 0; kk < 8; ++kk)
            wc[kk] = *(const bf16x8*)(w2u + nrow * 128 + (kk * 2 + kg) * 8);
        const float b2us = b2u[nrow];
        f32x16 cu0 = zero16(), cu1 = zero16();
        __builtin_amdgcn_s_setprio(1);
#pragma unroll
        for (int kk = 0; kk < 8; ++kk) {
            int ch = kk * 2 + kg;
            cu0 = mfma16(ld256(ttr, ecol0, ch), wc[kk], cu0);
            cu1 = mfma16(ld256(ttr, ecol1, ch), wc[kk], cu1);
        }
        __builtin_amdgcn_s_setprio(0);
#pragma unroll
        for (int r = 0; r < 16; ++r) {
            int rmap = (r & 3) + 8 * (r >> 2) + 4 * kg;
            int ng0 = n0 + rmap;
            int ng1 = n0 + 32 + rmap;
            if (ng0 < NN) {
                size_t o = (size_t)ng0 * 128 + nrow;
                outp[o] = cu0[r] + b2us + h[o];
            }
            if (ng1 < NN) {
                size_t o = (size_t)ng1 * 128 + nrow;
                outp[o] = cu1[r] + b2us + h[o];
            }
        }
    }
}

extern "C" void kernel_launch(void* const* d_in, const int* in_sizes, int n_in,
                              void* d_out, int out_size, void* d_ws, size_t ws_size,
                              hipStream_t stream) {
    const float* h   = (const float*)d_in[0];
    const int* edges = (const int*)d_in[1];
    const float* W1m = (const float*)d_in[2];
    const float* b1m = (const float*)d_in[3];
    const float* W2m = (const float*)d_in[4];
    const float* b2m = (const float*)d_in[5];
    const float* W1u = (const float*)d_in[6];
    const float* b1u = (const float*)d_in[7];
    const float* W2u = (const float*)d_in[8];
    const float* b2u = (const float*)d_in[9];
    float* out = (float*)d_out;

    char* ws = (char*)d_ws;
    u16* w1tm  = (u16*)(ws + 0);
    u16* w2tm  = (u16*)(ws + 65536);
    u16* w1tu  = (u16*)(ws + 98304);
    u16* w2tu  = (u16*)(ws + 163840);
    int* curs  = (int*)(ws + 196608);
    u32* elist = (u32*)(ws + 200704);    // NT*CAP*4 = 3,203,072
    u16* hb    = (u16*)(ws + 3403776);   // 12,800,000
    int use_hb = (ws_size >= 3403776ull + (size_t)NN * 128 * 2) ? 1 : 0;

    (void)hipFuncSetAttribute((const void*)fused_kernel,
                              hipFuncAttributeMaxDynamicSharedMemorySize, SMEM_TOTAL);

    hipMemsetAsync(curs, 0, NT * sizeof(int), stream);
    prep_kernel<<<512, 256, 0, stream>>>(h, W1m, W2m, W1u, W2u,
                                         w1tm, w2tm, w1tu, w2tu, hb, use_hb);
    scatter_kernel<<<(NE + 2047) / 2048, 256, 0, stream>>>(edges, elist, curs);
    fused_kernel<<<NT, 256, SMEM_TOTAL, stream>>>(h, hb, use_hb, elist, curs,
                                                  w1tm, w2tm, w1tu, w2tu,
                                                  b1m, b2m, b1u, b2u, out);
}

// Round 18
// 145.936 us; speedup vs baseline: 1.0567x; 1.0567x over previous
//
#include <hip/hip_runtime.h>
#include <hip/hip_bf16.h>

#define NN 50000
#define NE 600000
#define TN 64                       // nodes per dst-tile
#define NT ((NN + TN - 1) / TN)     // 782 tiles
#define CAP 1024                    // bucket capacity (avg 768)
#define PREP_BLOCKS 512
#define SCAT_BLOCKS ((NE + 2047) / 2048)

typedef unsigned short u16;
typedef unsigned int u32;
typedef unsigned long long u64;
typedef __attribute__((ext_vector_type(8))) short bf16x8;
typedef __attribute__((ext_vector_type(16))) float f32x16;
typedef __attribute__((ext_vector_type(4))) int int4v;

// ---------- LDS layout (49 KiB) ----------
#define SM_AB   0        // 16K: pr [64 e][128 k] / hid [64 e][128 n1] / aggL [64 d][128 n]
#define SM_TT   16384    // 16K: prologue ht (256B rows) -> tt [128 n1][64 d] (128B rows) -> upd hiddenU
#define SM_ST   32768    // 8K: St [64 e][64 d] single-buffered
#define SM_S    40960    // 8K: S  [64 d][64 e] single-buffered
#define SM_BIAS 49152    // 1K: b1m f32[128] @+0, b1u f32[128] @+512
#define SMEM_TOTAL 50176
// upd phase: ht restaged over St+S (16K contiguous @32768); hiddenU over TT region

// LDS-only barrier: no vmcnt drain (prefetch stays in flight)
__device__ __forceinline__ void bar_lds() {
    asm volatile("s_waitcnt lgkmcnt(0)" ::: "memory");
    __builtin_amdgcn_s_barrier();
}

__device__ __forceinline__ u16 f2b(float x) {
    __hip_bfloat16 b = __float2bfloat16(x);
    union { __hip_bfloat16 b; u16 u; } c; c.b = b; return c.u;
}
__device__ __forceinline__ int4v zero4() {
    int4v v; v[0]=0; v[1]=0; v[2]=0; v[3]=0; return v;
}
__device__ __forceinline__ f32x16 zero16() {
    f32x16 z;
#pragma unroll
    for (int i = 0; i < 16; ++i) z[i] = 0.f;
    return z;
}
__device__ __forceinline__ int4v cvt8(const float* __restrict__ p) {
    const float4* q = (const float4*)p;
    float4 f0 = q[0], f1 = q[1];
    union { u16 u[8]; int4v v; } r;
    r.u[0]=f2b(f0.x); r.u[1]=f2b(f0.y); r.u[2]=f2b(f0.z); r.u[3]=f2b(f0.w);
    r.u[4]=f2b(f1.x); r.u[5]=f2b(f1.y); r.u[6]=f2b(f1.z); r.u[7]=f2b(f1.w);
    return r.v;
}
__device__ __forceinline__ u64 pack4(float a, float b, float c, float d) {
    union { u16 u[4]; u64 q; } r;
    r.u[0]=f2b(a); r.u[1]=f2b(b); r.u[2]=f2b(c); r.u[3]=f2b(d); return r.q;
}
__device__ __forceinline__ f32x16 mfma16(bf16x8 a, bf16x8 b, f32x16 c) {
    return __builtin_amdgcn_mfma_f32_32x32x16_bf16(a, b, c, 0, 0, 0);
}
// 256B-row buffers (16 chunks), 4-bit XOR swizzle
__device__ __forceinline__ bf16x8 ld256(const char* base, int row, int c) {
    return *(const bf16x8*)(base + row * 256 + ((c ^ (row & 15)) << 4));
}
// 128B-row buffers (8 chunks), 3-bit XOR swizzle
__device__ __forceinline__ bf16x8 ld128r(const char* base, int row, int c) {
    return *(const bf16x8*)(base + row * 128 + ((c ^ (row & 7)) << 4));
}

// ---------------- combined setup: blocks [0,512) prep; [512, 512+293) scatter ----------------
// curs must be zeroed by a prior stream-ordered memset (done in kernel_launch).
__global__ __launch_bounds__(256) void setup_kernel(
    const float* __restrict__ h,
    const float* __restrict__ W1m, const float* __restrict__ W2m,
    const float* __restrict__ W1u, const float* __restrict__ W2u,
    u16* __restrict__ w1tm, u16* __restrict__ w2tm,
    u16* __restrict__ w1tu, u16* __restrict__ w2tu,
    u16* __restrict__ hbuf, int do_h,
    const int* __restrict__ edges, u32* __restrict__ elist, int* __restrict__ cursor)
{
    __shared__ int lcnt[NT];
    if (blockIdx.x < PREP_BLOCKS) {
        int tid = blockIdx.x * blockDim.x + threadIdx.x;
        int stride = PREP_BLOCKS * 256;
        for (int i = tid; i < 128 * 256; i += stride) {
            int n = i >> 8, k = i & 255;
            w1tm[i] = f2b(W1m[k * 128 + n]);
            w1tu[i] = f2b(W1u[k * 128 + n]);
        }
        for (int i = tid; i < 128 * 128; i += stride) {
            int n = i >> 7, k = i & 127;
            w2tm[i] = f2b(W2m[k * 128 + n]);
            w2tu[i] = f2b(W2u[k * 128 + n]);
        }
        if (do_h) {
            for (int i = tid; i < NN * 128 / 8; i += stride)
                *(int4v*)(hbuf + (size_t)i * 8) = cvt8(h + (size_t)i * 8);
        }
    } else {
        const int e0 = (blockIdx.x - PREP_BLOCKS) * 2048;
        for (int i = threadIdx.x; i < NT; i += 256) lcnt[i] = 0;
        __syncthreads();
#pragma unroll
        for (int k = 0; k < 8; ++k) {
            int e = e0 + k * 256 + threadIdx.x;
            if (e < NE) atomicAdd(&lcnt[edges[2 * e + 1] >> 6], 1);
        }
        __syncthreads();
        for (int i = threadIdx.x; i < NT; i += 256) {
            int cn = lcnt[i];
            if (cn > 0) lcnt[i] = atomicAdd(&cursor[i], cn);
        }
        __syncthreads();
#pragma unroll
        for (int k = 0; k < 8; ++k) {
            int e = e0 + k * 256 + threadIdx.x;
            if (e < NE) {
                int s = edges[2 * e], d = edges[2 * e + 1];
                int bin = d >> 6;
                int pos = atomicAdd(&lcnt[bin], 1);
                if (pos < CAP) elist[(size_t)bin * CAP + pos] = (u32)s | ((u32)(d & 63) << 16);
            }
        }
    }
}

// ---------------- fused per-dst-tile: 4 waves, each covers both e-halves (R16 verbatim) ----------------
__global__ __launch_bounds__(256, 2) void fused_kernel(
    const float* __restrict__ h, const u16* __restrict__ hb, int use_hb,
    const u32* __restrict__ elist, const int* __restrict__ cursor,
    const u16* __restrict__ w1m, const u16* __restrict__ w2m,
    const u16* __restrict__ w1u, const u16* __restrict__ w2u,
    const float* __restrict__ b1m, const float* __restrict__ b2m,
    const float* __restrict__ b1u, const float* __restrict__ b2u,
    float* __restrict__ outp)
{
    extern __shared__ char sm[];
    char* ab   = sm + SM_AB;      // pr / hid / aggL
    char* ttr  = sm + SM_TT;      // prologue ht -> tt -> upd hiddenU
    char* Stb  = sm + SM_ST;      // St [64 e][64 d]
    char* Sb   = sm + SM_S;       // S  [64 d][64 e]
    char* bias = sm + SM_BIAS;
    char* htu  = sm + SM_ST;      // upd-phase ht (St+S dead, 16K contiguous)

    const int tid  = threadIdx.x;
    const int lane = tid & 63;
    const int wid  = tid >> 6;          // 0..3 = wn (n-block)
    const int l31  = lane & 31;
    const int kg   = lane >> 5;
    const int nrow  = wid * 32 + l31;   // output-feature index
    const int ecol0 = l31;              // e/d/node index, half 0
    const int ecol1 = 32 + l31;         // half 1

    const int bin = blockIdx.x;
    const int n0  = bin * TN;
    int size = cursor[bin]; if (size > CAP) size = CAP;
    const u32* el = elist + (size_t)bin * CAP;
    const int nchunk = (size + 63) >> 6;

    // ---- persistent weight fragments (32+32 VGPR) ----
    bf16x8 w1f[8], w2f[8];
#pragma unroll
    for (int kk = 0; kk < 8; ++kk) {
        w1f[kk] = *(const bf16x8*)(w1m + nrow * 256 + (kk * 2 + kg) * 8);   // src half
        w2f[kk] = *(const bf16x8*)(w2m + nrow * 128 + (kk * 2 + kg) * 8);
    }
    const float b2ms = b2m[nrow];

    // ---- stage prologue-ht into TT region; bias tables; zero St+S (16K) ----
    for (int i = tid; i < 1024; i += 256) {
        int row = i >> 4, c = i & 15;
        int node = n0 + row;
        int4v v = zero4();
        if (node < NN) {
            if (use_hb) v = *(const int4v*)(hb + (size_t)node * 128 + c * 8);
            else        v = cvt8(h + (size_t)node * 128 + c * 8);
        }
        *(int4v*)(ttr + row * 256 + ((c ^ (row & 15)) << 4)) = v;
    }
    if (tid < 32)      *(float4*)(bias + tid * 16)          = ((const float4*)b1m)[tid];
    else if (tid < 64) *(float4*)(bias + 512 + (tid-32)*16) = ((const float4*)b1u)[tid - 32];
    {
        char* z = sm + SM_ST + tid * 64;   // St + S = 16K
        *(int4v*)z = zero4(); *(int4v*)(z + 16) = zero4();
        *(int4v*)(z + 32) = zero4(); *(int4v*)(z + 48) = zero4();
    }

    // St writer (wave 0, same-lane ordered): row = e-slot (lane), col = d
    auto put_St = [&](u32 rec, int cb2, u16 val) {
        if (cb2 + lane < size) {
            int d = (int)((rec >> 16) & 63);
            *(u16*)(Stb + lane * 128 + (((d >> 3) ^ (lane & 7)) << 4) + (d & 7) * 2) = val;
        }
    };
    // S writer (wave 0): row = d, col = e-slot (lane)
    auto put_S = [&](u32 rec, int cb2, u16 val) {
        if (cb2 + lane < size) {
            int d = (int)((rec >> 16) & 63);
            *(u16*)(Sb + d * 128 + (((lane >> 3) ^ (d & 7)) << 4) + (lane & 7) * 2) = val;
        }
    };

    // src gather staging: thread -> rows (tid>>4 + 16u, u=0..3) x 16B chunk (tid&15)
    const int s_row0 = tid >> 4, s_cc = tid & 15;
    auto stage_load = [&](u32 dle_c, int cb2, int4v* v) {
#pragma unroll
        for (int u = 0; u < 4; ++u) {
            int row = s_row0 + 16 * u;
            int s = ((int)__shfl((int)dle_c, row, 64)) & 0xFFFF;
            v[u] = zero4();
            if (cb2 + row < size)
                v[u] = use_hb ? *(const int4v*)(hb + (size_t)s * 128 + s_cc * 8)
                              : cvt8(h + (size_t)s * 128 + s_cc * 8);
        }
    };
    auto stage_write = [&](const int4v* v) {
#pragma unroll
        for (int u = 0; u < 4; ++u) {
            int row = s_row0 + 16 * u;
            *(int4v*)(ab + row * 256 + ((s_cc ^ (row & 15)) << 4)) = v[u];
        }
    };

    // in-register msg transpose: C-layout f32x16 (+bias) -> two A-frags (16 e each)
    auto mkfrags = [&](const f32x16& cc, bf16x8& lo, bf16x8& hi) {
        u32 u0,u1,u2,u3,u4,u5,u6,u7;
        {
            float a0=cc[0]+b2ms, a1=cc[1]+b2ms, a2=cc[2]+b2ms, a3=cc[3]+b2ms;
            float a4=cc[4]+b2ms, a5=cc[5]+b2ms, a6=cc[6]+b2ms, a7=cc[7]+b2ms;
            float a8=cc[8]+b2ms, a9=cc[9]+b2ms, aA=cc[10]+b2ms, aB=cc[11]+b2ms;
            float aC=cc[12]+b2ms, aD=cc[13]+b2ms, aE=cc[14]+b2ms, aF=cc[15]+b2ms;
            asm("v_cvt_pk_bf16_f32 %0, %1, %2" : "=v"(u0) : "v"(a0), "v"(a1));
            asm("v_cvt_pk_bf16_f32 %0, %1, %2" : "=v"(u1) : "v"(a2), "v"(a3));
            asm("v_cvt_pk_bf16_f32 %0, %1, %2" : "=v"(u2) : "v"(a4), "v"(a5));
            asm("v_cvt_pk_bf16_f32 %0, %1, %2" : "=v"(u3) : "v"(a6), "v"(a7));
            asm("v_cvt_pk_bf16_f32 %0, %1, %2" : "=v"(u4) : "v"(a8), "v"(a9));
            asm("v_cvt_pk_bf16_f32 %0, %1, %2" : "=v"(u5) : "v"(aA), "v"(aB));
            asm("v_cvt_pk_bf16_f32 %0, %1, %2" : "=v"(u6) : "v"(aC), "v"(aD));
            asm("v_cvt_pk_bf16_f32 %0, %1, %2" : "=v"(u7) : "v"(aE), "v"(aF));
        }
        asm volatile("v_permlane32_swap_b32 %0, %1" : "+v"(u0), "+v"(u2));
        asm volatile("v_permlane32_swap_b32 %0, %1" : "+v"(u1), "+v"(u3));
        asm volatile("v_permlane32_swap_b32 %0, %1" : "+v"(u4), "+v"(u6));
        asm volatile("v_permlane32_swap_b32 %0, %1" : "+v"(u5), "+v"(u7));
        union { u32 w[4]; bf16x8 v; } A, B;
        A.w[0]=u0; A.w[1]=u1; A.w[2]=u2; A.w[3]=u3;
        B.w[0]=u4; B.w[1]=u5; B.w[2]=u6; B.w[3]=u7;
        lo = A.v; hi = B.v;
    };

    u32 dle = (lane < size) ? el[lane] : 0u;     // chunk 0 edge records
    if (nchunk > 0) {
        int4v v[4];
        stage_load(dle, 0, v);
        stage_write(v);
    }
    __syncthreads();   // ht(ttr) / bias / St+S-zero / pr0 ready

    // ---- T-compute: reads ht from TT region; wave0 sets St+S for chunk 0 ----
    f32x16 t0 = zero16(), t1 = zero16();
    {
        __builtin_amdgcn_s_setprio(1);
#pragma unroll
        for (int kk = 0; kk < 8; ++kk) {
            bf16x8 wtf = *(const bf16x8*)(w1m + nrow * 256 + (16 + kk * 2 + kg) * 8);
            int ch = kk * 2 + kg;
            t0 = mfma16(wtf, ld256(ttr, ecol0, ch), t0);
            t1 = mfma16(wtf, ld256(ttr, ecol1, ch), t1);
        }
        __builtin_amdgcn_s_setprio(0);
    }
    if (wid == 0) { put_St(dle, 0, 0x3F80); put_S(dle, 0, 0x3F80); }
    bar_lds();   // all ht reads done -> TT region reusable as tt

    // write Tt into TT region ([128 n1][64 d], 128B rows, 3-bit swz)
#pragma unroll
    for (int r = 0; r < 16; ++r) {
        int n1 = wid * 32 + (r & 3) + 8 * (r >> 2) + 4 * kg;
        *(u16*)(ttr + n1 * 128 + (((ecol0 >> 3) ^ (n1 & 7)) << 4) + (ecol0 & 7) * 2) = f2b(t0[r]);
        *(u16*)(ttr + n1 * 128 + (((ecol1 >> 3) ^ (n1 & 7)) << 4) + (ecol1 & 7) * 2) = f2b(t1[r]);
    }
    bar_lds();   // tt + St + S ready

    // ---- chunk loop: 4 barriers ----
    f32x16 aggT0 = zero16(), aggT1 = zero16();
    u32 dle_prev = 0;
    for (int c = 0; c < nchunk; ++c) {
        const int cb = c << 6;
        const bool havepf = (c + 1 < nchunk);

        u32 dle_next = (havepf && (cb + 64 + lane < size)) ? el[cb + 64 + lane] : 0u;

        // ---- P0: GEMM1 (swapped) -> mm[n1][e], both e-halves ----
        f32x16 mm0 = zero16(), mm1 = zero16();
        __builtin_amdgcn_s_setprio(1);
#pragma unroll
        for (int kk = 0; kk < 4; ++kk) {
            int ch = kk * 2 + kg;
            bf16x8 ttf = ld128r(ttr, nrow, ch);           // shared across halves
            mm0 = mfma16(ttf, ld128r(Stb, ecol0, ch), mm0);
            mm1 = mfma16(ttf, ld128r(Stb, ecol1, ch), mm1);
        }
#pragma unroll
        for (int kk = 0; kk < 8; ++kk) {
            int ch = kk * 2 + kg;
            mm0 = mfma16(w1f[kk], ld256(ab, ecol0, ch), mm0);
            mm1 = mfma16(w1f[kk], ld256(ab, ecol1, ch), mm1);
        }
        __builtin_amdgcn_s_setprio(0);
        bar_lds();   // pr + St reads done

        // ---- P1: gather issue; epi1 -> hidden into ab; wave0 St/S clear+set ----
        int4v v[4];
        if (havepf) stage_load(dle_next, cb + 64, v);   // global loads in flight
#pragma unroll
        for (int rq = 0; rq < 4; ++rq) {
            float4 bq = *(const float4*)(bias + (wid * 32 + 8 * rq + 4 * kg) * 4);
            int cch = wid * 4 + rq;
            u64 q0 = pack4(fmaxf(mm0[4 * rq + 0] + bq.x, 0.f),
                           fmaxf(mm0[4 * rq + 1] + bq.y, 0.f),
                           fmaxf(mm0[4 * rq + 2] + bq.z, 0.f),
                           fmaxf(mm0[4 * rq + 3] + bq.w, 0.f));
            u64 q1 = pack4(fmaxf(mm1[4 * rq + 0] + bq.x, 0.f),
                           fmaxf(mm1[4 * rq + 1] + bq.y, 0.f),
                           fmaxf(mm1[4 * rq + 2] + bq.z, 0.f),
                           fmaxf(mm1[4 * rq + 3] + bq.w, 0.f));
            *(u64*)(ab + ecol0 * 256 + ((cch ^ (ecol0 & 15)) << 4) + 8 * kg) = q0;
            *(u64*)(ab + ecol1 * 256 + ((cch ^ (ecol1 & 15)) << 4) + 8 * kg) = q1;
        }
        if (wid == 0) {
            if (c > 0) put_S(dle_prev, cb - 64, 0);   // clear prev chunk's S (read finished at P2(c-1))
            put_St(dle, cb, 0);                       // clear cur St (read finished at P0 bar)
            asm volatile("s_waitcnt lgkmcnt(0)" ::: "memory");
            put_St(dle_next, cb + 64, 0x3F80);        // set next St (no-op on last chunk)
            put_S(dle, cb, 0x3F80);                   // (re)set cur S for P2
        }
        bar_lds();   // hidden ready; St/S updated

        // ---- P2: GEMM2 -> c20/c21; in-reg transpose; segsum aggT += msg @ S ----
        {
            f32x16 c20 = zero16(), c21 = zero16();
            __builtin_amdgcn_s_setprio(1);
#pragma unroll
            for (int kk = 0; kk < 8; ++kk) {
                int ch = kk * 2 + kg;
                c20 = mfma16(ld256(ab, ecol0, ch), w2f[kk], c20);
                c21 = mfma16(ld256(ab, ecol1, ch), w2f[kk], c21);
            }
            __builtin_amdgcn_s_setprio(0);
            bf16x8 fA, fB, fC, fD;
            mkfrags(c20, fA, fB);     // e 0..15, 16..31
            mkfrags(c21, fC, fD);     // e 32..47, 48..63
            __builtin_amdgcn_s_setprio(1);
            aggT0 = mfma16(fA, ld128r(Sb, ecol0, 0 + kg), aggT0);
            aggT1 = mfma16(fA, ld128r(Sb, ecol1, 0 + kg), aggT1);
            aggT0 = mfma16(fB, ld128r(Sb, ecol0, 2 + kg), aggT0);
            aggT1 = mfma16(fB, ld128r(Sb, ecol1, 2 + kg), aggT1);
            aggT0 = mfma16(fC, ld128r(Sb, ecol0, 4 + kg), aggT0);
            aggT1 = mfma16(fC, ld128r(Sb, ecol1, 4 + kg), aggT1);
            aggT0 = mfma16(fD, ld128r(Sb, ecol0, 6 + kg), aggT0);
            aggT1 = mfma16(fD, ld128r(Sb, ecol1, 6 + kg), aggT1);
            __builtin_amdgcn_s_setprio(0);
        }
        bar_lds();   // ab (hid) reads done

        // ---- P3: stage next pr into ab ----
        if (havepf) stage_write(v);
        bar_lds();   // next pr ready
        dle_prev = dle;
        dle = dle_next;
    }

    // ---- upd phase: dump aggT -> aggL in ab; restage ht into St+S region ----
#pragma unroll
    for (int rq = 0; rq < 4; ++rq) {
        int cch = wid * 4 + rq;
        u64 q0 = pack4(aggT0[4 * rq + 0], aggT0[4 * rq + 1], aggT0[4 * rq + 2], aggT0[4 * rq + 3]);
        u64 q1 = pack4(aggT1[4 * rq + 0], aggT1[4 * rq + 1], aggT1[4 * rq + 2], aggT1[4 * rq + 3]);
        *(u64*)(ab + ecol0 * 256 + ((cch ^ (ecol0 & 15)) << 4) + 8 * kg) = q0;
        *(u64*)(ab + ecol1 * 256 + ((cch ^ (ecol1 & 15)) << 4) + 8 * kg) = q1;
    }
    for (int i = tid; i < 1024; i += 256) {
        int row = i >> 4, c = i & 15;
        int node = n0 + row;
        int4v v = zero4();
        if (node < NN) {
            if (use_hb) v = *(const int4v*)(hb + (size_t)node * 128 + c * 8);
            else        v = cvt8(h + (size_t)node * 128 + c * 8);
        }
        *(int4v*)(htu + row * 256 + ((c ^ (row & 15)) << 4)) = v;
    }
    bar_lds();   // aggL + ht ready

    // upd GEMM1 (swapped): au[n1][node] = W1u @ [ht | aggL]^T
    {
        f32x16 au0 = zero16(), au1 = zero16();
        {
            bf16x8 wa[8];
#pragma unroll
            for (int kk = 0; kk < 8; ++kk)
                wa[kk] = *(const bf16x8*)(w1u + nrow * 256 + (kk * 2 + kg) * 8);
            __builtin_amdgcn_s_setprio(1);
#pragma unroll
            for (int kk = 0; kk < 8; ++kk) {
                int ch = kk * 2 + kg;
                au0 = mfma16(wa[kk], ld256(htu, ecol0, ch), au0);
                au1 = mfma16(wa[kk], ld256(htu, ecol1, ch), au1);
            }
            __builtin_amdgcn_s_setprio(0);
        }
        {
            bf16x8 wbf[8];
#pragma unroll
            for (int kk = 0; kk < 8; ++kk)
                wbf[kk] = *(const bf16x8*)(w1u + nrow * 256 + ((8 + kk) * 2 + kg) * 8);
            __builtin_amdgcn_s_setprio(1);
#pragma unroll
            for (int kk = 0; kk < 8; ++kk) {
                int ch = kk * 2 + kg;
                au0 = mfma16(wbf[kk], ld256(ab, ecol0, ch), au0);
                au1 = mfma16(wbf[kk], ld256(ab, ecol1, ch), au1);
            }
            __builtin_amdgcn_s_setprio(0);
        }
        bar_lds();   // htu reads done -> TT region writable (hiddenU)
        // epiU1 -> hiddenU[node][n1] into TT region (256B rows), bias from LDS
#pragma unroll
        for (int rq = 0; rq < 4; ++rq) {
            float4 bq = *(const float4*)(bias + 512 + (wid * 32 + 8 * rq + 4 * kg) * 4);
            int cch = wid * 4 + rq;
            u64 q0 = pack4(fmaxf(au0[4 * rq + 0] + bq.x, 0.f),
                           fmaxf(au0[4 * rq + 1] + bq.y, 0.f),
                           fmaxf(au0[4 * rq + 2] + bq.z, 0.f),
                           fmaxf(au0[4 * rq + 3] + bq.w, 0.f));
            u64 q1 = pack4(fmaxf(au1[4 * rq + 0] + bq.x, 0.f),
                           fmaxf(au1[4 * rq + 1] + bq.y, 0.f),
                           fmaxf(au1[4 * rq + 2] + bq.z, 0.f),
                           fmaxf(au1[4 * rq + 3] + bq.w, 0.f));
            *(u64*)(ttr + ecol0 * 256 + ((cch ^ (ecol0 & 15)) << 4) + 8 * kg) = q0;
            *(u64*)(ttr + ecol1 * 256 + ((cch ^ (ecol1 & 15)) << 4) + 8 * kg) = q1;
        }
    }
    bar_lds();

    // upd GEMM2 (direct): out[node][n2] = hiddenU @ W2u + b2u + h
    {
        bf16x8 wc[8];
#pragma unroll
        for (int kk = 0; kk < 8; ++kk)
            wc[kk] = *(const bf16x8*)(w2u + nrow * 128 + (kk * 2 + kg) * 8);
        const float b2us = b2u[nrow];
        f32x16 cu0 = zero16(), cu1 = zero16();
        __builtin_amdgcn_s_setprio(1);
#pragma unroll
        for (int kk = 0; kk < 8; ++kk) {
            int ch = kk * 2 + kg;
            cu0 = mfma16(ld256(ttr, ecol0, ch), wc[kk], cu0);
            cu1 = mfma16(ld256(ttr, ecol1, ch), wc[kk], cu1);
        }
        __builtin_amdgcn_s_setprio(0);
#pragma unroll
        for (int r = 0; r < 16; ++r) {
            int rmap = (r & 3) + 8 * (r >> 2) + 4 * kg;
            int ng0 = n0 + rmap;
            int ng1 = n0 + 32 + rmap;
            if (ng0 < NN) {
                size_t o = (size_t)ng0 * 128 + nrow;
                outp[o] = cu0[r] + b2us + h[o];
            }
            if (ng1 < NN) {
                size_t o = (size_t)ng1 * 128 + nrow;
                outp[o] = cu1[r] + b2us + h[o];
            }
        }
    }
}

extern "C" void kernel_launch(void* const* d_in, const int* in_sizes, int n_in,
                              void* d_out, int out_size, void* d_ws, size_t ws_size,
                              hipStream_t stream) {
    const float* h   = (const float*)d_in[0];
    const int* edges = (const int*)d_in[1];
    const float* W1m = (const float*)d_in[2];
    const float* b1m = (const float*)d_in[3];
    const float* W2m = (const float*)d_in[4];
    const float* b2m = (const float*)d_in[5];
    const float* W1u = (const float*)d_in[6];
    const float* b1u = (const float*)d_in[7];
    const float* W2u = (const float*)d_in[8];
    const float* b2u = (const float*)d_in[9];
    float* out = (float*)d_out;

    char* ws = (char*)d_ws;
    u16* w1tm  = (u16*)(ws + 0);
    u16* w2tm  = (u16*)(ws + 65536);
    u16* w1tu  = (u16*)(ws + 98304);
    u16* w2tu  = (u16*)(ws + 163840);
    int* curs  = (int*)(ws + 196608);
    u32* elist = (u32*)(ws + 200704);    // NT*CAP*4 = 3,203,072
    u16* hb    = (u16*)(ws + 3403776);   // 12,800,000
    int use_hb = (ws_size >= 3403776ull + (size_t)NN * 128 * 2) ? 1 : 0;

    (void)hipFuncSetAttribute((const void*)fused_kernel,
                              hipFuncAttributeMaxDynamicSharedMemorySize, SMEM_TOTAL);

    hipMemsetAsync(curs, 0, NT * sizeof(int), stream);
    setup_kernel<<<PREP_BLOCKS + SCAT_BLOCKS, 256, 0, stream>>>(
        h, W1m, W2m, W1u, W2u, w1tm, w2tm, w1tu, w2tu, hb, use_hb,
        edges, elist, curs);
    fused_kernel<<<NT, 256, SMEM_TOTAL, stream>>>(h, hb, use_hb, elist, curs,
                                                  w1tm, w2tm, w1tu, w2tu,
                                                  b1m, b2m, b1u, b2u, out);
}